// Round 6
// baseline (131.231 us; speedup 1.0000x reference)
//
#include <hip/hip_runtime.h>
#include <cstdint>

#define DD 128
#define SB 128   // scan blocks

typedef __attribute__((ext_vector_type(8))) short bf16x8;
typedef __attribute__((ext_vector_type(4))) float f32x4;

__device__ __forceinline__ short f2bf(float f) {
    union { float f; unsigned u; } v; v.f = f;
    unsigned r = v.u + 0x7FFFu + ((v.u >> 16) & 1u);   // RNE
    return (short)(r >> 16);
}
__device__ __forceinline__ float bf2f(unsigned short s) {
    union { unsigned u; float f; } v; v.u = ((unsigned)s) << 16;
    return v.f;
}

__device__ __forceinline__ int load_idx(const void* ei, int flag, long long pos) {
    if (flag) return ((const int*)ei)[pos];
    return (int)((const long long*)ei)[pos];
}

// Zero cnt[N] with int4 stores (runtime hipMemsetAsync's fillBuffer kernel
// measured 42 us -- tiny latency-bound grid; this does it at full BW).
__global__ __launch_bounds__(256) void zero_kernel(int4* __restrict__ p, int n4) {
    int i = blockIdx.x * 256 + threadIdx.x;
    if (i < n4) p[i] = make_int4(0, 0, 0, 0);
}

// ---------------------------------------------------------------------------
// Merged detect+count. Each block redundantly detects int32-vs-int64 from the
// first 256 int64-slots (L2-hot). A packed-int32 slot misreads as >=2^32
// unless its hi int32 is 0 (p = 2e-5); 256 slots -> miss prob ~0.
// flag=1 -> int32, flag=0 -> int64.
// ---------------------------------------------------------------------------
__global__ __launch_bounds__(256) void count_kernel(const void* ei, int E,
                                                    int* flag_out, int* cnt) {
    __shared__ int s_flag;
    if (threadIdx.x == 0) s_flag = 0;
    __syncthreads();
    const long long* p = (const long long*)ei;
    int n = E < 256 ? E : 256;
    int bad = 0;
    if (threadIdx.x < n) {
        long long v = p[threadIdx.x];
        if (v < 0 || v >= (1LL << 32)) bad = 1;
    }
    if (bad) atomicOr(&s_flag, 1);
    __syncthreads();
    const int f = s_flag;
    if (blockIdx.x == 0 && threadIdx.x == 0) *flag_out = f;

    int e = blockIdx.x * 256 + threadIdx.x;
    if (e < E) {
        int t = load_idx(ei, f, (long long)E + e);
        atomicAdd(&cnt[t], 1);
    }
}

// ---------------------------------------------------------------------------
// Multi-block exclusive scan of cnt[N] -> row_ptr/cursor, fused dis.
// scan_part also packs W -> Wp (bf16, transposed) with its spare threads.
// ---------------------------------------------------------------------------
__global__ __launch_bounds__(256) void scan_part(const int* __restrict__ cnt, int N,
                                                 int* __restrict__ bsum,
                                                 const float* __restrict__ W,
                                                 short* __restrict__ Wp) {
    const int gi = blockIdx.x * 256 + threadIdx.x;
    if (gi < DD * DD) {
        const int k = gi >> 7, n = gi & 127;
        Wp[n * DD + k] = f2bf(W[gi]);
    }

    const int ch = (N + SB - 1) / SB;
    const int beg = blockIdx.x * ch;
    const int end = min(beg + ch, N);
    int lsum = 0;
    for (int i = beg + threadIdx.x; i < end; i += 256) lsum += cnt[i];
    __shared__ int s[256];
    s[threadIdx.x] = lsum;
    __syncthreads();
    for (int off = 128; off > 0; off >>= 1) {
        if (threadIdx.x < off) s[threadIdx.x] += s[threadIdx.x + off];
        __syncthreads();
    }
    if (threadIdx.x == 0) bsum[blockIdx.x] = s[0];
}

__global__ __launch_bounds__(SB) void scan_mid(const int* __restrict__ bsum,
                                               int* __restrict__ bbase,
                                               int* __restrict__ row_ptr, int N) {
    __shared__ int s[SB];
    int tid = threadIdx.x;
    s[tid] = bsum[tid];
    __syncthreads();
    for (int off = 1; off < SB; off <<= 1) {
        int v = (tid >= off) ? s[tid - off] : 0;
        __syncthreads();
        s[tid] += v;
        __syncthreads();
    }
    bbase[tid] = (tid == 0) ? 0 : s[tid - 1];
    if (tid == SB - 1) row_ptr[N] = s[SB - 1];
}

__global__ __launch_bounds__(256) void scan_final(const int* __restrict__ cnt, int N,
                                                  const int* __restrict__ bbase,
                                                  int* __restrict__ row_ptr,
                                                  int* __restrict__ cursor,
                                                  float* __restrict__ dis) {
    const int ch = (N + SB - 1) / SB;
    const int tch = (ch + 255) / 256;
    const int beg = blockIdx.x * ch;
    const int tid = threadIdx.x;

    int tbeg = beg + tid * tch;
    int tend = min(tbeg + tch, min(beg + ch, N));
    int lsum = 0;
    for (int i = tbeg; i < tend; ++i) lsum += cnt[i];

    __shared__ int s[256];
    s[tid] = lsum;
    __syncthreads();
    for (int off = 1; off < 256; off <<= 1) {
        int v = (tid >= off) ? s[tid - off] : 0;
        __syncthreads();
        s[tid] += v;
        __syncthreads();
    }
    int prefix = bbase[blockIdx.x] + ((tid == 0) ? 0 : s[tid - 1]);
    for (int i = tbeg; i < tend; ++i) {
        int c = cnt[i];
        row_ptr[i] = prefix;
        cursor[i]  = prefix;
        dis[i] = rsqrtf((float)(c + 1));   // +1 self-loop
        prefix += c;
    }
}

// Bucket-fill: col[pos] = src for each edge, pos allocated per-dst cursor.
__global__ __launch_bounds__(256) void fill_kernel(const void* ei, int E, const int* flag,
                                                   int* cursor, int* col) {
    int e = blockIdx.x * 256 + threadIdx.x;
    if (e >= E) return;
    int f = *flag;
    int s = load_idx(ei, f, e);
    int t = load_idx(ei, f, (long long)E + e);
    int pos = atomicAdd(&cursor[t], 1);
    col[pos] = s;
}

// ---------------------------------------------------------------------------
// xws[row] = bf16( (x[row] @ W) * dis[row] )  via mfma_f32_16x16x32_bf16.
// ---------------------------------------------------------------------------
__global__ __launch_bounds__(256) void gemm_mfma(const float* __restrict__ x,
                                                 const short* __restrict__ Wp,
                                                 const float* __restrict__ dis,
                                                 short* __restrict__ xws, int N) {
    const int tid = threadIdx.x;
    const int wave = tid >> 6;
    const int lane = tid & 63;
    const int lmod = lane & 15;
    const int lgrp = lane >> 4;
    const int rowbase = blockIdx.x * 64 + wave * 16;
    const int arow = rowbase + lmod;
    const bool aok = arow < N;

    f32x4 acc[8];
#pragma unroll
    for (int i = 0; i < 8; ++i) acc[i] = (f32x4){0.f, 0.f, 0.f, 0.f};

#pragma unroll
    for (int ks = 0; ks < 4; ++ks) {
        const int kbase = ks * 32 + lgrp * 8;
        bf16x8 afrag;
        if (aok) {
            const float4 a0 = *(const float4*)&x[(size_t)arow * DD + kbase];
            const float4 a1 = *(const float4*)&x[(size_t)arow * DD + kbase + 4];
            afrag[0] = f2bf(a0.x); afrag[1] = f2bf(a0.y);
            afrag[2] = f2bf(a0.z); afrag[3] = f2bf(a0.w);
            afrag[4] = f2bf(a1.x); afrag[5] = f2bf(a1.y);
            afrag[6] = f2bf(a1.z); afrag[7] = f2bf(a1.w);
        } else {
#pragma unroll
            for (int i = 0; i < 8; ++i) afrag[i] = 0;
        }
#pragma unroll
        for (int nt = 0; nt < 8; ++nt) {
            bf16x8 bfrag = *(const bf16x8*)&Wp[(nt * 16 + lmod) * DD + kbase];
            acc[nt] = __builtin_amdgcn_mfma_f32_16x16x32_bf16(afrag, bfrag, acc[nt], 0, 0, 0);
        }
    }

#pragma unroll
    for (int r = 0; r < 4; ++r) {
        const int row = rowbase + lgrp * 4 + r;
        if (row < N) {
            const float ds = dis[row];
#pragma unroll
            for (int nt = 0; nt < 8; ++nt)
                xws[(size_t)row * DD + nt * 16 + lmod] = f2bf(acc[nt][r] * ds);
        }
    }
}

// ---------------------------------------------------------------------------
// Pull-gather (bf16 rows): out[t] = x[t] + b + dis[t]*(xws[t] + sum xws[col_e])
// Half-wave per node; 4x-unrolled edge loop, 4 gathers in flight, dual
// accumulator sets to break the fadd dependency chain.
// ---------------------------------------------------------------------------
__global__ __launch_bounds__(256) void gather_kernel(const short* __restrict__ xws,
                                                     const float* __restrict__ x,
                                                     const float* __restrict__ b,
                                                     const float* __restrict__ dis,
                                                     const int* __restrict__ row_ptr,
                                                     const int* __restrict__ col,
                                                     float* __restrict__ out, int N) {
    const int node = blockIdx.x * 8 + (threadIdx.x >> 5);
    if (node >= N) return;
    const int lane = threadIdx.x & 31;
    const ushort4* xw4 = (const ushort4*)xws;
    const size_t base = (size_t)node * 32 + lane;

    const float  d  = dis[node];
    const float4 xv = ((const float4*)x)[base];
    const float4 bv = ((const float4*)b)[lane];

    ushort4 sv = xw4[base];                       // self-loop term (pre-scaled)
    float a0 = bf2f(sv.x), a1 = bf2f(sv.y), a2 = bf2f(sv.z), a3 = bf2f(sv.w);
    float c0 = 0.f, c1 = 0.f, c2 = 0.f, c3 = 0.f;

    const int beg = row_ptr[node], end = row_ptr[node + 1];
    int i = beg;
    for (; i + 4 <= end; i += 4) {
        const int s0 = col[i], s1 = col[i + 1], s2 = col[i + 2], s3 = col[i + 3];
        const ushort4 v0 = xw4[(size_t)s0 * 32 + lane];
        const ushort4 v1 = xw4[(size_t)s1 * 32 + lane];
        const ushort4 v2 = xw4[(size_t)s2 * 32 + lane];
        const ushort4 v3 = xw4[(size_t)s3 * 32 + lane];
        a0 += bf2f(v0.x); a1 += bf2f(v0.y); a2 += bf2f(v0.z); a3 += bf2f(v0.w);
        c0 += bf2f(v1.x); c1 += bf2f(v1.y); c2 += bf2f(v1.z); c3 += bf2f(v1.w);
        a0 += bf2f(v2.x); a1 += bf2f(v2.y); a2 += bf2f(v2.z); a3 += bf2f(v2.w);
        c0 += bf2f(v3.x); c1 += bf2f(v3.y); c2 += bf2f(v3.z); c3 += bf2f(v3.w);
    }
    for (; i < end; ++i) {
        const ushort4 v = xw4[(size_t)col[i] * 32 + lane];
        a0 += bf2f(v.x); a1 += bf2f(v.y); a2 += bf2f(v.z); a3 += bf2f(v.w);
    }
    a0 += c0; a1 += c1; a2 += c2; a3 += c3;

    float4 o;
    o.x = xv.x + bv.x + d * a0;
    o.y = xv.y + bv.y + d * a1;
    o.z = xv.z + bv.z + d * a2;
    o.w = xv.w + bv.w + d * a3;
    ((float4*)out)[base] = o;
}

extern "C" void kernel_launch(void* const* d_in, const int* in_sizes, int n_in,
                              void* d_out, int out_size, void* d_ws, size_t ws_size,
                              hipStream_t stream) {
    const float* x  = (const float*)d_in[0];
    const void*  ei = d_in[1];
    const float* W  = (const float*)d_in[2];
    const float* b  = (const float*)d_in[3];
    float* out = (float*)d_out;

    const int N = in_sizes[0] / DD;
    const int E = in_sizes[1] / 2;

    // Workspace: flag | bsum | bbase | cnt(16-al) | dis | row_ptr | cursor | col | Wp | xws
    char* ws = (char*)d_ws;
    int*   flag    = (int*)ws;
    int*   bsum    = (int*)(ws + 256);
    int*   bbase   = bsum + SB;
    int*   cnt     = bbase + SB;            // offset 256+1024 = 1280, 16B-aligned
    float* dis     = (float*)(cnt + N);
    int*   row_ptr = (int*)(dis + N);
    int*   cursor  = row_ptr + (N + 1);
    int*   col     = cursor + N;
    size_t off = 256 + (size_t)SB * 8 + (size_t)N * 16 + 4 + (size_t)E * 4;
    off = (off + 255) & ~(size_t)255;
    short* Wp  = (short*)(ws + off);
    off += (size_t)DD * DD * 2;             // 32 KB, keeps 256 alignment
    short* xws = (short*)(ws + off);

    const int n4 = (N + 3) / 4;             // N assumed %4==0 (50000); tail ints
    zero_kernel<<<(n4 + 255) / 256, 256, 0, stream>>>((int4*)cnt, n4);
    count_kernel<<<(E + 255) / 256, 256, 0, stream>>>(ei, E, flag, cnt);
    scan_part<<<SB, 256, 0, stream>>>(cnt, N, bsum, W, Wp);
    scan_mid<<<1, SB, 0, stream>>>(bsum, bbase, row_ptr, N);
    scan_final<<<SB, 256, 0, stream>>>(cnt, N, bbase, row_ptr, cursor, dis);
    gemm_mfma<<<(N + 63) / 64, 256, 0, stream>>>(x, Wp, dis, xws, N);
    fill_kernel<<<(E + 255) / 256, 256, 0, stream>>>(ei, E, flag, cursor, col);
    gather_kernel<<<(N + 7) / 8, 256, 0, stream>>>(xws, x, b, dis, row_ptr, col, out, N);
}